// Round 1
// baseline (13162.881 us; speedup 1.0000x reference)
//
#include <hip/hip_runtime.h>
#include <stdint.h>

typedef unsigned short u16;

#define T_STEPS 512
#define BATCH   64
#define DIN     512
#define HID     1024
#define G4      4096   // 4*HID
#define NBLK    128
#define NH      8      // hidden units per block
#define NC      32     // gate columns per block (4*NH)
#define THREADS 512

#define U_LD    1032   // 1024 + 8 pad (bank-spread, keeps 16B align)
#define W_LD    520    // 512 + 8 pad

typedef float f32x4 __attribute__((ext_vector_type(4)));
typedef short bf16x8 __attribute__((ext_vector_type(8)));

__device__ __forceinline__ u16 f2bf(float f) {
  unsigned u = __float_as_uint(f);
  u += 0x7fffu + ((u >> 16) & 1u);   // RNE
  return (u16)(u >> 16);
}

// x[B][T][D] fp32  ->  xb[T][B][D] bf16  (so step t's A-operand rows are contiguous)
__global__ void cvt_x(const float* __restrict__ x, u16* __restrict__ xb) {
  int i = blockIdx.x * 256 + threadIdx.x;     // over T*B*(D/8) = 2,097,152
  int dblk = i & 63;
  int rest = i >> 6;
  int b = rest & 63;
  int t = rest >> 6;
  const float4* s = reinterpret_cast<const float4*>(x + ((size_t)(b * T_STEPS + t)) * DIN + dblk * 8);
  float4 f0 = s[0], f1 = s[1];
  uint4 o;
  o.x = (unsigned)f2bf(f0.x) | ((unsigned)f2bf(f0.y) << 16);
  o.y = (unsigned)f2bf(f0.z) | ((unsigned)f2bf(f0.w) << 16);
  o.z = (unsigned)f2bf(f1.x) | ((unsigned)f2bf(f1.y) << 16);
  o.w = (unsigned)f2bf(f1.z) | ((unsigned)f2bf(f1.w) << 16);
  *reinterpret_cast<uint4*>(xb + ((size_t)(t * BATCH + b)) * DIN + dblk * 8) = o;
}

// Persistent LSTM. Block bid owns hidden units [bid*NH, bid*NH+NH).
// GEMM orientation: M=batch(64), N=NC(32), K=DIN then HID.
// 8 waves = 4 M-tiles x 2 N-tiles of 16x16x32 MFMA.
__launch_bounds__(THREADS)
__global__ void lstm_kernel(const float* __restrict__ W, const float* __restrict__ U,
                            const float* __restrict__ bias, const u16* __restrict__ xb,
                            u16* __restrict__ hbuf, float* __restrict__ out,
                            unsigned* __restrict__ bar) {
  __shared__ u16 Ut[NC * U_LD];        // U^T slice: [col][k]
  __shared__ u16 Wt[NC * W_LD];        // W^T slice: [col][k]
  __shared__ float zsm[BATCH * 33];    // z tile [b][n], padded stride

  const int tid = threadIdx.x;
  const int bid = blockIdx.x;
  const int j0 = bid * NH;

  // One-time: load + transpose + bf16-convert this block's weight slices.
  // LDS col c = gate*NH + u  <->  global col = gate*1024 + j0 + u
  for (int idx = tid; idx < NC * HID; idx += THREADS) {
    int c = idx & (NC - 1);
    int k = idx >> 5;
    int gcol = ((c >> 3) << 10) + j0 + (c & 7);
    Ut[c * U_LD + k] = f2bf(U[(size_t)k * G4 + gcol]);
  }
  for (int idx = tid; idx < NC * DIN; idx += THREADS) {
    int c = idx & (NC - 1);
    int k = idx >> 5;
    int gcol = ((c >> 3) << 10) + j0 + (c & 7);
    Wt[c * W_LD + k] = f2bf(W[(size_t)k * G4 + gcol]);
  }
  __syncthreads();

  // MFMA lane geometry
  const int l   = tid & 63;
  const int wv  = tid >> 6;
  const int m_t = wv & 3;          // M-tile (batch/16)
  const int n_t = wv >> 2;         // N-tile (cols/16)
  const int arow = m_t * 16 + (l & 15);   // batch row for A
  const int kg   = l >> 4;                // k-group 0..3
  const int bcol = n_t * 16 + (l & 15);   // LDS weight col for B
  const u16* ubp = &Ut[bcol * U_LD + kg * 8];
  const u16* wbp = &Wt[bcol * W_LD + kg * 8];

  // Phase-B (gate update) assignment: thread -> (batch pb, unit pu)
  const int pb = tid & 63;
  const int pu = tid >> 6;
  float c_reg = 0.f;
  const float bi  = bias[j0 + pu];
  const float bff = bias[1024 + j0 + pu];
  const float bg  = bias[2048 + j0 + pu];
  const float bo  = bias[3072 + j0 + pu];

  unsigned target = 0;
  for (int t = 0; t < T_STEPS; ++t) {
    f32x4 acc = {0.f, 0.f, 0.f, 0.f};
    // x_t @ W  (h-independent)
    const u16* xa = xb + (size_t)t * (BATCH * DIN) + arow * DIN + kg * 8;
#pragma unroll 8
    for (int kt = 0; kt < DIN / 32; ++kt) {
      bf16x8 av = *reinterpret_cast<const bf16x8*>(xa + kt * 32);
      bf16x8 bv = *reinterpret_cast<const bf16x8*>(wbp + kt * 32);
      acc = __builtin_amdgcn_mfma_f32_16x16x32_bf16(av, bv, acc, 0, 0, 0);
    }
    // h @ U
    const u16* ha = hbuf + (size_t)(t & 1) * (BATCH * HID) + arow * HID + kg * 8;
#pragma unroll 8
    for (int kt = 0; kt < HID / 32; ++kt) {
      bf16x8 av = *reinterpret_cast<const bf16x8*>(ha + kt * 32);
      bf16x8 bv = *reinterpret_cast<const bf16x8*>(ubp + kt * 32);
      acc = __builtin_amdgcn_mfma_f32_16x16x32_bf16(av, bv, acc, 0, 0, 0);
    }
    // C/D layout: col = lane&15, row = (lane>>4)*4 + reg
#pragma unroll
    for (int r = 0; r < 4; ++r)
      zsm[(m_t * 16 + kg * 4 + r) * 33 + bcol] = acc[r];
    __syncthreads();

    // Gate update: one thread per (batch, unit)
    float zi = zsm[pb * 33 + pu]      + bi;
    float zf = zsm[pb * 33 + 8 + pu]  + bff;
    float zg = zsm[pb * 33 + 16 + pu] + bg;
    float zo = zsm[pb * 33 + 24 + pu] + bo;
    float ig = 1.f / (1.f + __expf(-zi));
    float fg = 1.f / (1.f + __expf(-zf));
    float og = 1.f / (1.f + __expf(-zo));
    float gg = tanhf(zg);
    c_reg = fg * c_reg + ig * gg;
    float h = og * tanhf(c_reg);
    hbuf[(size_t)((t + 1) & 1) * (BATCH * HID) + pb * HID + j0 + pu] = f2bf(h);
    if (t == T_STEPS - 1) {
      float* orow = out + (size_t)pb * 3072 + j0 + pu;
      orow[0]    = h;       // h_T
      orow[1024] = h;       // h_T again
      orow[2048] = c_reg;   // c_T
    }
    __syncthreads();              // all hbuf stores issued
    // Device-scope grid barrier (monotone counter; 128 blocks co-resident by construction)
    target += NBLK;
    if (tid == 0) {
      __threadfence();
      __hip_atomic_fetch_add(bar, 1u, __ATOMIC_RELEASE, __HIP_MEMORY_SCOPE_AGENT);
      while (__hip_atomic_load(bar, __ATOMIC_RELAXED, __HIP_MEMORY_SCOPE_AGENT) < target) {}
      __threadfence();
    }
    __syncthreads();
  }
}

extern "C" void kernel_launch(void* const* d_in, const int* in_sizes, int n_in,
                              void* d_out, int out_size, void* d_ws, size_t ws_size,
                              hipStream_t stream) {
  const float* x = (const float*)d_in[0];
  const float* W = (const float*)d_in[1];
  const float* U = (const float*)d_in[2];
  const float* b = (const float*)d_in[3];
  float* out = (float*)d_out;

  const size_t xb_bytes   = (size_t)T_STEPS * BATCH * DIN * sizeof(u16);  // 32 MB
  const size_t hbuf_bytes = 2ull * BATCH * HID * sizeof(u16);             // 256 KB
  if (ws_size < xb_bytes + hbuf_bytes + 64) return;  // loud failure: output stays zero

  u16* xb        = (u16*)d_ws;
  u16* hbuf      = (u16*)((char*)d_ws + xb_bytes);
  unsigned* bar  = (unsigned*)((char*)d_ws + xb_bytes + hbuf_bytes);

  // zero h0 (both buffers) + barrier counter — replayed every graph launch
  hipMemsetAsync((void*)hbuf, 0, hbuf_bytes + 64, stream);
  cvt_x<<<(T_STEPS * BATCH * DIN / 8 + 255) / 256, 256, 0, stream>>>(x, xb);
  lstm_kernel<<<NBLK, THREADS, 0, stream>>>(W, U, b, xb, hbuf, out, bar);
}

// Round 2
// 6306.963 us; speedup vs baseline: 2.0870x; 2.0870x over previous
//
#include <hip/hip_runtime.h>
#include <stdint.h>

typedef unsigned short u16;

#define T_STEPS 512
#define BATCH   64
#define DIN     512
#define HID     1024
#define G4      4096   // 4*HID
#define NBLK    128
#define NH      8      // hidden units per block
#define NC      32     // gate columns per block (4*NH)
#define THREADS 512

#define U_LD    1032   // 1024 + 8 pad
#define W_LD    520    // 512 + 8 pad

typedef float f32x4 __attribute__((ext_vector_type(4)));
typedef short bf16x8 __attribute__((ext_vector_type(8)));

__device__ __forceinline__ u16 f2bf(float f) {
  unsigned u = __float_as_uint(f);
  u += 0x7fffu + ((u >> 16) & 1u);   // RNE
  return (u16)(u >> 16);
}

// x[B][T][D] fp32  ->  xb[T][B][D] bf16
__global__ void cvt_x(const float* __restrict__ x, u16* __restrict__ xb) {
  int i = blockIdx.x * 256 + threadIdx.x;     // over T*B*(D/8)
  int dblk = i & 63;
  int rest = i >> 6;
  int b = rest & 63;
  int t = rest >> 6;
  const float4* s = reinterpret_cast<const float4*>(x + ((size_t)(b * T_STEPS + t)) * DIN + dblk * 8);
  float4 f0 = s[0], f1 = s[1];
  uint4 o;
  o.x = (unsigned)f2bf(f0.x) | ((unsigned)f2bf(f0.y) << 16);
  o.y = (unsigned)f2bf(f0.z) | ((unsigned)f2bf(f0.w) << 16);
  o.z = (unsigned)f2bf(f1.x) | ((unsigned)f2bf(f1.y) << 16);
  o.w = (unsigned)f2bf(f1.z) | ((unsigned)f2bf(f1.w) << 16);
  *reinterpret_cast<uint4*>(xb + ((size_t)(t * BATCH + b)) * DIN + dblk * 8) = o;
}

// Persistent LSTM. Block bid owns hidden units [bid*8, bid*8+8).
// h exchange layout: hbuf[buf][kblk(128)][batch(64)][8] bf16 — block-private 1KB
// write region (no cross-XCD false sharing), and 8 k-contiguous elems per
// (kblk,batch) so MFMA A-fragments are contiguous 16B loads.
__launch_bounds__(THREADS)
__global__ void lstm_kernel(const float* __restrict__ W, const float* __restrict__ U,
                            const float* __restrict__ bias, const u16* __restrict__ xb,
                            u16* __restrict__ hbuf, float* __restrict__ out,
                            unsigned* __restrict__ flags) {
  __shared__ u16 Ut[NC * U_LD];        // U^T slice: [col][k]
  __shared__ u16 Wt[NC * W_LD];        // W^T slice: [col][k]
  __shared__ float zsm[BATCH * 33];    // z tile [b][n]

  const int tid = threadIdx.x;
  const int bid = blockIdx.x;
  const int j0 = bid * NH;

  // One-time: load + transpose + bf16-convert weight slices.
  for (int idx = tid; idx < NC * HID; idx += THREADS) {
    int c = idx & (NC - 1);
    int k = idx >> 5;
    int gcol = ((c >> 3) << 10) + j0 + (c & 7);
    Ut[c * U_LD + k] = f2bf(U[(size_t)k * G4 + gcol]);
  }
  for (int idx = tid; idx < NC * DIN; idx += THREADS) {
    int c = idx & (NC - 1);
    int k = idx >> 5;
    int gcol = ((c >> 3) << 10) + j0 + (c & 7);
    Wt[c * W_LD + k] = f2bf(W[(size_t)k * G4 + gcol]);
  }
  __syncthreads();

  // MFMA lane geometry (16x16x32: A lane holds row=l&15, k=(l>>4)*8+i)
  const int l   = tid & 63;
  const int wv  = tid >> 6;
  const int m_t = wv & 3;          // M-tile (batch/16)
  const int n_t = wv >> 2;         // N-tile (cols/16)
  const int arow = m_t * 16 + (l & 15);
  const int kg   = l >> 4;
  const int bcol = n_t * 16 + (l & 15);
  const u16* ubp = &Ut[bcol * U_LD + kg * 8];
  const u16* wbp = &Wt[bcol * W_LD + kg * 8];

  // bias for this lane's output column (same col for all 4 acc regs)
  const float bb = bias[((bcol >> 3) << 10) + j0 + (bcol & 7)];

  // Gate-update assignment: thread -> (batch pb, unit pu)
  const int pb = tid & 63;
  const int pu = tid >> 6;
  float c_reg = 0.f;

  for (int t = 0; t < T_STEPS; ++t) {
    f32x4 acc = {bb, bb, bb, bb};

    // ---- x_t @ W (h-independent; overlaps other blocks finishing t-1) ----
    const u16* xa = xb + (size_t)t * (BATCH * DIN) + arow * DIN + kg * 8;
#pragma unroll 8
    for (int kt = 0; kt < DIN / 32; ++kt) {
      bf16x8 av = *reinterpret_cast<const bf16x8*>(xa + kt * 32);
      bf16x8 bv = *reinterpret_cast<const bf16x8*>(wbp + kt * 32);
      acc = __builtin_amdgcn_mfma_f32_16x16x32_bf16(av, bv, acc, 0, 0, 0);
    }

    // ---- wait for h_t (flags monotone; flags[j*4] >= t means h_t ready) ----
    if (wv == 0) {
      while (true) {
        unsigned f1 = __hip_atomic_load(&flags[l * 4],       __ATOMIC_RELAXED, __HIP_MEMORY_SCOPE_AGENT);
        unsigned f2 = __hip_atomic_load(&flags[256 + l * 4], __ATOMIC_RELAXED, __HIP_MEMORY_SCOPE_AGENT);
        if (__all(f1 >= (unsigned)t && f2 >= (unsigned)t)) break;
        __builtin_amdgcn_s_sleep(1);
      }
      __threadfence();   // acquire: make other blocks' h stores visible
    }
    __syncthreads();

    // ---- h_t @ U ----
    const u16* ha = hbuf + (size_t)(t & 1) * (BATCH * HID) + kg * 512 + arow * 8;
#pragma unroll 8
    for (int kt = 0; kt < HID / 32; ++kt) {
      bf16x8 av = *reinterpret_cast<const bf16x8*>(ha + kt * 2048);
      bf16x8 bv = *reinterpret_cast<const bf16x8*>(ubp + kt * 32);
      acc = __builtin_amdgcn_mfma_f32_16x16x32_bf16(av, bv, acc, 0, 0, 0);
    }
    // C/D layout: col = lane&15, row = (lane>>4)*4 + reg
#pragma unroll
    for (int r = 0; r < 4; ++r)
      zsm[(m_t * 16 + kg * 4 + r) * 33 + bcol] = acc[r];
    __syncthreads();

    // ---- gates: one thread per (batch, unit) ----
    float zi = zsm[pb * 33 + pu];
    float zf = zsm[pb * 33 + 8 + pu];
    float zg = zsm[pb * 33 + 16 + pu];
    float zo = zsm[pb * 33 + 24 + pu];
    float ig = 1.f / (1.f + __expf(-zi));
    float fg = 1.f / (1.f + __expf(-zf));
    float og = 1.f / (1.f + __expf(-zo));
    float gg = tanhf(zg);
    c_reg = fg * c_reg + ig * gg;
    float h = og * tanhf(c_reg);
    // packed, block-private write region: [(bid*64 + pb)*8 + pu]
    hbuf[(size_t)((t + 1) & 1) * (BATCH * HID) + (size_t)(bid * 64 + pb) * 8 + pu] = f2bf(h);
    if (t == T_STEPS - 1) {
      float* orow = out + (size_t)pb * 3072 + j0 + pu;
      orow[0]    = h;       // h_T
      orow[1024] = h;       // h_T again
      orow[2048] = c_reg;   // c_T
    }
    __syncthreads();              // all h stores + zsm reads done
    if (tid == 0) {
      __threadfence();            // release: h stores visible before flag
      __hip_atomic_store(&flags[bid * 4], (unsigned)(t + 1), __ATOMIC_RELAXED, __HIP_MEMORY_SCOPE_AGENT);
    }
    // no extra barrier: next iter touches only xb/W-LDS until its own poll
  }
}

extern "C" void kernel_launch(void* const* d_in, const int* in_sizes, int n_in,
                              void* d_out, int out_size, void* d_ws, size_t ws_size,
                              hipStream_t stream) {
  const float* x = (const float*)d_in[0];
  const float* W = (const float*)d_in[1];
  const float* U = (const float*)d_in[2];
  const float* b = (const float*)d_in[3];
  float* out = (float*)d_out;

  const size_t xb_bytes   = (size_t)T_STEPS * BATCH * DIN * sizeof(u16);  // 32 MB
  const size_t hbuf_bytes = 2ull * BATCH * HID * sizeof(u16);             // 256 KB
  const size_t flag_bytes = NBLK * 16;                                    // 2 KB
  if (ws_size < xb_bytes + hbuf_bytes + flag_bytes) return;

  u16* xb        = (u16*)d_ws;
  u16* hbuf      = (u16*)((char*)d_ws + xb_bytes);
  unsigned* flags = (unsigned*)((char*)d_ws + xb_bytes + hbuf_bytes);

  // zero h0 (both buffers) + flags — replayed every graph launch
  hipMemsetAsync((void*)hbuf, 0, hbuf_bytes + flag_bytes, stream);
  cvt_x<<<(T_STEPS * BATCH * DIN / 8 + 255) / 256, 256, 0, stream>>>(x, xb);
  lstm_kernel<<<NBLK, THREADS, 0, stream>>>(W, U, b, xb, hbuf, out, flags);
}

// Round 4
// 3682.918 us; speedup vs baseline: 3.5740x; 1.7125x over previous
//
#include <hip/hip_runtime.h>
#include <stdint.h>

typedef unsigned short u16;

#define T_STEPS 512
#define BATCH   64
#define DIN     512
#define HID     1024
#define G4      4096   // 4*HID
#define NBLK    128
#define NH      8      // hidden units per block
#define NC      32     // gate columns per block (4*NH)
#define THREADS 512

#define U_LD    1032   // 1024 + 8 pad
#define W_LD    520    // 512 + 8 pad

typedef float f32x4 __attribute__((ext_vector_type(4)));
typedef short bf16x8 __attribute__((ext_vector_type(8)));
typedef unsigned uint32x4 __attribute__((ext_vector_type(4)));

__device__ __forceinline__ u16 f2bf(float f) {
  unsigned u = __float_as_uint(f);
  u += 0x7fffu + ((u >> 16) & 1u);   // RNE
  return (u16)(u >> 16);
}

// Coherent (L1+L2-bypass, served at the L3 coherence point) access helpers.
// Flat-address form: addr in a 64-bit VGPR pair ("v" constraint), `off` saddr.
__device__ __forceinline__ uint32x4 load16_sc(uint64_t addr) {
  uint32x4 d;
  asm volatile("global_load_dwordx4 %0, %1, off sc0 sc1"
               : "=v"(d) : "v"(addr));
  return d;
}
__device__ __forceinline__ unsigned load4_sc(uint64_t addr) {
  unsigned d;
  asm volatile("global_load_dword %0, %1, off sc0 sc1"
               : "=v"(d) : "v"(addr));
  return d;
}
__device__ __forceinline__ void store16_sc(uint64_t addr, uint32x4 v) {
  asm volatile("global_store_dwordx4 %0, %1, off sc0 sc1"
               :: "v"(addr), "v"(v) : "memory");
}
__device__ __forceinline__ void store4_sc(uint64_t addr, unsigned v) {
  asm volatile("global_store_dword %0, %1, off sc0 sc1"
               :: "v"(addr), "v"(v) : "memory");
}
#define WAITV(n) asm volatile("s_waitcnt vmcnt(" #n ")" ::: "memory")

// x[B][T][D] fp32  ->  xb[T][B][D] bf16
__global__ void cvt_x(const float* __restrict__ x, u16* __restrict__ xb) {
  int i = blockIdx.x * 256 + threadIdx.x;     // over T*B*(D/8)
  int dblk = i & 63;
  int rest = i >> 6;
  int b = rest & 63;
  int t = rest >> 6;
  const float4* s = reinterpret_cast<const float4*>(x + ((size_t)(b * T_STEPS + t)) * DIN + dblk * 8);
  float4 f0 = s[0], f1 = s[1];
  uint4 o;
  o.x = (unsigned)f2bf(f0.x) | ((unsigned)f2bf(f0.y) << 16);
  o.y = (unsigned)f2bf(f0.z) | ((unsigned)f2bf(f0.w) << 16);
  o.z = (unsigned)f2bf(f1.x) | ((unsigned)f2bf(f1.y) << 16);
  o.w = (unsigned)f2bf(f1.z) | ((unsigned)f2bf(f1.w) << 16);
  *reinterpret_cast<uint4*>(xb + ((size_t)(t * BATCH + b)) * DIN + dblk * 8) = o;
}

// Persistent LSTM. Block bid owns hidden units [bid*8, bid*8+8).
// h exchange layout: hbuf[buf][kblk(128)][batch(64)][8] bf16 — block-private 1KB
// write region; all h/flag traffic via sc0 sc1 (no wbl2/inv in the loop).
__launch_bounds__(THREADS)
__global__ void lstm_kernel(const float* __restrict__ W, const float* __restrict__ U,
                            const float* __restrict__ bias, const u16* __restrict__ xb,
                            u16* __restrict__ hbuf, float* __restrict__ out,
                            unsigned* __restrict__ flags) {
  __shared__ u16 Ut[NC * U_LD];        // U^T slice: [col][k]
  __shared__ u16 Wt[NC * W_LD];        // W^T slice: [col][k]
  __shared__ float zsm[BATCH * 33];    // z tile [b][n]
  __shared__ u16 hstage[BATCH * 8];    // h staging: [b][8 units], 16B rows

  const int tid = threadIdx.x;
  const int bid = blockIdx.x;
  const int j0 = bid * NH;

  // One-time: load + transpose + bf16-convert weight slices.
  for (int idx = tid; idx < NC * HID; idx += THREADS) {
    int c = idx & (NC - 1);
    int k = idx >> 5;
    int gcol = ((c >> 3) << 10) + j0 + (c & 7);
    Ut[c * U_LD + k] = f2bf(U[(size_t)k * G4 + gcol]);
  }
  for (int idx = tid; idx < NC * DIN; idx += THREADS) {
    int c = idx & (NC - 1);
    int k = idx >> 5;
    int gcol = ((c >> 3) << 10) + j0 + (c & 7);
    Wt[c * W_LD + k] = f2bf(W[(size_t)k * G4 + gcol]);
  }
  __syncthreads();

  // MFMA lane geometry (16x16x32: A lane holds row=l&15, k=(l>>4)*8+i)
  const int l   = tid & 63;
  const int wv  = tid >> 6;
  const int m_t = wv & 3;          // M-tile (batch/16)
  const int n_t = wv >> 2;         // N-tile (cols/16)
  const int arow = m_t * 16 + (l & 15);
  const int kg   = l >> 4;
  const int bcol = n_t * 16 + (l & 15);
  const u16* ubp = &Ut[bcol * U_LD + kg * 8];
  const u16* wbp = &Wt[bcol * W_LD + kg * 8];

  const float bb = bias[((bcol >> 3) << 10) + j0 + (bcol & 7)];

  const int pb = tid & 63;
  const int pu = tid >> 6;
  float c_reg = 0.f;

  const int vo0 = arow * 16 + kg * 1024;   // byte offset of this lane's h fragment

#define HLOAD(buf, ktbase) do { _Pragma("unroll") for (int i_ = 0; i_ < 8; ++i_) \
    buf[i_] = load16_sc(hb + vo0 + (ktbase + i_) * 4096); } while (0)
#define HCHUNK(buf, ktbase) do { _Pragma("unroll") for (int i_ = 0; i_ < 8; ++i_) { \
    bf16x8 av_ = __builtin_bit_cast(bf16x8, buf[i_]); \
    bf16x8 bv_ = *reinterpret_cast<const bf16x8*>(ubp + (ktbase + i_) * 32); \
    acc = __builtin_amdgcn_mfma_f32_16x16x32_bf16(av_, bv_, acc, 0, 0, 0); } } while (0)

  for (int t = 0; t < T_STEPS; ++t) {
    f32x4 acc = {bb, bb, bb, bb};

    // ---- x_t @ W (h-independent; overlaps other blocks finishing t-1) ----
    const u16* xa = xb + (size_t)t * (BATCH * DIN) + arow * DIN + kg * 8;
#pragma unroll 8
    for (int kt = 0; kt < DIN / 32; ++kt) {
      bf16x8 av = *reinterpret_cast<const bf16x8*>(xa + kt * 32);
      bf16x8 bv = *reinterpret_cast<const bf16x8*>(wbp + kt * 32);
      acc = __builtin_amdgcn_mfma_f32_16x16x32_bf16(av, bv, acc, 0, 0, 0);
    }

    // ---- wait for h_t (flags monotone, sc1 loads; flags[j*4] >= t) ----
    const uint64_t fbase = (uint64_t)flags;
    if (wv == 0) {
      while (true) {
        unsigned f1 = load4_sc(fbase + l * 16);
        unsigned f2 = load4_sc(fbase + 1024 + l * 16);
        WAITV(0);
        if (__all(f1 >= (unsigned)t && f2 >= (unsigned)t)) break;
        __builtin_amdgcn_s_sleep(2);
      }
    }
    __syncthreads();

    // ---- h_t @ U : sc1 loads, 2-deep software pipeline, counted vmcnt ----
    const uint64_t hb = (uint64_t)hbuf + (uint64_t)(t & 1) * (BATCH * HID * 2);
    WAITV(0);                      // drain x-path loads so counts below are exact
    uint32x4 ra[8], rb[8];
    HLOAD(ra, 0);
    HLOAD(rb, 8);
    WAITV(8); __builtin_amdgcn_sched_barrier(0);
    HCHUNK(ra, 0);
    HLOAD(ra, 16);
    WAITV(8); __builtin_amdgcn_sched_barrier(0);
    HCHUNK(rb, 8);
    HLOAD(rb, 24);
    WAITV(8); __builtin_amdgcn_sched_barrier(0);
    HCHUNK(ra, 16);
    WAITV(0); __builtin_amdgcn_sched_barrier(0);
    HCHUNK(rb, 24);

    // C/D layout: col = lane&15, row = (lane>>4)*4 + reg
#pragma unroll
    for (int r = 0; r < 4; ++r)
      zsm[(m_t * 16 + kg * 4 + r) * 33 + bcol] = acc[r];
    __syncthreads();

    // ---- gates: one thread per (batch, unit) ----
    float zi = zsm[pb * 33 + pu];
    float zf = zsm[pb * 33 + 8 + pu];
    float zg = zsm[pb * 33 + 16 + pu];
    float zo = zsm[pb * 33 + 24 + pu];
    float ig = 1.f / (1.f + __expf(-zi));
    float fg = 1.f / (1.f + __expf(-zf));
    float og = 1.f / (1.f + __expf(-zo));
    float gg = tanhf(zg);
    c_reg = fg * c_reg + ig * gg;
    float h = og * tanhf(c_reg);
    hstage[pb * 8 + pu] = f2bf(h);
    if (t == T_STEPS - 1) {
      float* orow = out + (size_t)pb * 3072 + j0 + pu;
      orow[0]    = h;       // h_T
      orow[1024] = h;       // h_T again
      orow[2048] = c_reg;   // c_T
    }
    __syncthreads();              // hstage complete, zsm reads done

    // ---- publish h_{t+1}: wave 0 only; release via waitcnt (no wbl2) ----
    if (wv == 0) {
      uint32x4 hv = *reinterpret_cast<const uint32x4*>(&hstage[l * 8]);
      uint64_t hbn = (uint64_t)hbuf + (uint64_t)((t + 1) & 1) * (BATCH * HID * 2);
      store16_sc(hbn + bid * 1024 + l * 16, hv);
      WAITV(0);
      if (l == 0) store4_sc(fbase + bid * 16, (unsigned)(t + 1));
    }
    // no trailing barrier: next iter touches only xb/W-LDS until its own poll
  }
#undef HLOAD
#undef HCHUNK
}

extern "C" void kernel_launch(void* const* d_in, const int* in_sizes, int n_in,
                              void* d_out, int out_size, void* d_ws, size_t ws_size,
                              hipStream_t stream) {
  const float* x = (const float*)d_in[0];
  const float* W = (const float*)d_in[1];
  const float* U = (const float*)d_in[2];
  const float* b = (const float*)d_in[3];
  float* out = (float*)d_out;

  const size_t xb_bytes   = (size_t)T_STEPS * BATCH * DIN * sizeof(u16);  // 32 MB
  const size_t hbuf_bytes = 2ull * BATCH * HID * sizeof(u16);             // 256 KB
  const size_t flag_bytes = NBLK * 16;                                    // 2 KB
  if (ws_size < xb_bytes + hbuf_bytes + flag_bytes) return;

  u16* xb        = (u16*)d_ws;
  u16* hbuf      = (u16*)((char*)d_ws + xb_bytes);
  unsigned* flags = (unsigned*)((char*)d_ws + xb_bytes + hbuf_bytes);

  // zero h0 (both buffers) + flags — replayed every graph launch
  hipMemsetAsync((void*)hbuf, 0, hbuf_bytes + flag_bytes, stream);
  cvt_x<<<(T_STEPS * BATCH * DIN / 8 + 255) / 256, 256, 0, stream>>>(x, xb);
  lstm_kernel<<<NBLK, THREADS, 0, stream>>>(W, U, b, xb, hbuf, out, flags);
}

// Round 5
// 2892.442 us; speedup vs baseline: 4.5508x; 1.2733x over previous
//
#include <hip/hip_runtime.h>
#include <stdint.h>

typedef unsigned short u16;

#define T_STEPS 512
#define BATCH   64
#define DIN     512
#define HID     1024
#define G4      4096   // 4*HID
#define NBLK    128
#define NH      8      // hidden units per block
#define NC      32     // gate columns per block (4*NH)
#define THREADS 512

#define U_LD    1032   // 1024 + 8 pad (init staging only)
#define W_LD    520    // 512 + 8 pad  (init staging only)

// LDS: init phase  Ut[NC*U_LD] @0 (66048B), Wt[NC*W_LD] @66048 (33280B)
//      run  phase  zpart f32[4][64][33] @0 (33792B), hstage u16[512] @33792 (1024B)
#define SM_BYTES 99328
#define WT_OFF   66048
#define HS_OFF   33792

typedef float f32x16 __attribute__((ext_vector_type(16)));
typedef short bf16x8 __attribute__((ext_vector_type(8)));
typedef unsigned uint32x4 __attribute__((ext_vector_type(4)));

__device__ __forceinline__ u16 f2bf(float f) {
  unsigned u = __float_as_uint(f);
  u += 0x7fffu + ((u >> 16) & 1u);   // RNE
  return (u16)(u >> 16);
}
__device__ __forceinline__ float sigm(float x) {
  return __builtin_amdgcn_rcpf(1.f + __expf(-x));
}
__device__ __forceinline__ float fast_tanh(float x) {
  return 1.f - 2.f * __builtin_amdgcn_rcpf(__expf(2.f * x) + 1.f);
}

// Coherent (L2-bypass, served at coherence point) helpers; flat 64b VGPR addr.
__device__ __forceinline__ uint32x4 load16_sc(uint64_t addr) {
  uint32x4 d;
  asm volatile("global_load_dwordx4 %0, %1, off sc0 sc1" : "=v"(d) : "v"(addr));
  return d;
}
__device__ __forceinline__ unsigned load4_sc(uint64_t addr) {
  unsigned d;
  asm volatile("global_load_dword %0, %1, off sc0 sc1" : "=v"(d) : "v"(addr));
  return d;
}
__device__ __forceinline__ void store16_sc(uint64_t addr, uint32x4 v) {
  asm volatile("global_store_dwordx4 %0, %1, off sc0 sc1" :: "v"(addr), "v"(v) : "memory");
}
__device__ __forceinline__ void store4_sc(uint64_t addr, unsigned v) {
  asm volatile("global_store_dword %0, %1, off sc0 sc1" :: "v"(addr), "v"(v) : "memory");
}
#define WAITV(n) asm volatile("s_waitcnt vmcnt(" #n ")" ::: "memory")

// x[B][T][D] fp32 -> xb[T][B][D] bf16
__global__ void cvt_x(const float* __restrict__ x, u16* __restrict__ xb) {
  int i = blockIdx.x * 256 + threadIdx.x;
  int dblk = i & 63;
  int rest = i >> 6;
  int b = rest & 63;
  int t = rest >> 6;
  const float4* s = reinterpret_cast<const float4*>(x + ((size_t)(b * T_STEPS + t)) * DIN + dblk * 8);
  float4 f0 = s[0], f1 = s[1];
  uint4 o;
  o.x = (unsigned)f2bf(f0.x) | ((unsigned)f2bf(f0.y) << 16);
  o.y = (unsigned)f2bf(f0.z) | ((unsigned)f2bf(f0.w) << 16);
  o.z = (unsigned)f2bf(f1.x) | ((unsigned)f2bf(f1.y) << 16);
  o.w = (unsigned)f2bf(f1.z) | ((unsigned)f2bf(f1.w) << 16);
  *reinterpret_cast<uint4*>(xb + ((size_t)(t * BATCH + b)) * DIN + dblk * 8) = o;
}

// Persistent LSTM. Block bid owns hidden units [bid*8, bid*8+8).
// GEMM: 32x32x16 MFMA, 8 waves = 2 M-tiles x 4 K-splits; B-frags in registers;
// K-split partials reduced through LDS (zpart). h layout [kblk=128][b=64][8] bf16.
__launch_bounds__(THREADS)
__global__ void lstm_kernel(const float* __restrict__ W, const float* __restrict__ U,
                            const float* __restrict__ bias, const u16* __restrict__ xb,
                            u16* __restrict__ hbuf, float* __restrict__ out,
                            unsigned* __restrict__ flags) {
  __shared__ __align__(16) char smraw[SM_BYTES];
  u16* Ut = (u16*)smraw;
  u16* Wt = (u16*)(smraw + WT_OFF);
  float* zp = (float*)smraw;              // run phase: [4][64][33]
  u16* hstage = (u16*)(smraw + HS_OFF);   // run phase: [64][8]

  const int tid = threadIdx.x;
  const int bid = blockIdx.x;
  const int j0 = bid * NH;

  // ---- init: stage transposed bf16 weight slices ----
  for (int idx = tid; idx < NC * HID; idx += THREADS) {
    int c = idx & (NC - 1);
    int k = idx >> 5;
    int gcol = ((c >> 3) << 10) + j0 + (c & 7);
    Ut[c * U_LD + k] = f2bf(U[(size_t)k * G4 + gcol]);
  }
  for (int idx = tid; idx < NC * DIN; idx += THREADS) {
    int c = idx & (NC - 1);
    int k = idx >> 5;
    int gcol = ((c >> 3) << 10) + j0 + (c & 7);
    Wt[c * W_LD + k] = f2bf(W[(size_t)k * G4 + gcol]);
  }
  __syncthreads();

  // ---- wave geometry: wv = (ks<<1)|m_t ----
  const int l   = tid & 63;
  const int wv  = tid >> 6;
  const int m_t = wv & 1;          // batch rows m_t*32 .. +31
  const int ks  = wv >> 1;         // K-split 0..3 (256 of HID, 128 of DIN each)
  const int cl  = l & 31;          // A row within tile / B column
  const int q   = l >> 5;          // k-half of fragment

  // ---- persistent B fragments -> registers ----
  bf16x8 ubf[16], wbf[8];
  {
    const u16* ub = Ut + cl * U_LD + ks * 256 + q * 8;
#pragma unroll
    for (int s = 0; s < 16; ++s) ubf[s] = *(const bf16x8*)(ub + s * 16);
    const u16* wb = Wt + cl * W_LD + ks * 128 + q * 8;
#pragma unroll
    for (int s = 0; s < 8; ++s) wbf[s] = *(const bf16x8*)(wb + s * 16);
  }
  __syncthreads();   // staging dead; zpart/hstage live from here

  const int row = m_t * 32 + cl;   // batch row this lane loads for A
  const int pb = tid & 63;         // gates: batch
  const int pu = tid >> 6;         // gates: unit
  float c_reg = 0.f;
  const float bi  = bias[j0 + pu];
  const float bf_ = bias[1024 + j0 + pu];
  const float bg  = bias[2048 + j0 + pu];
  const float bo  = bias[3072 + j0 + pu];

  const uint64_t fbase = (uint64_t)flags;
  // h A-frag: kblk = ks*32 + s*2 + q, byte = kblk*1024 + row*16
  const uint64_t hlane = (uint64_t)(ks * 32 + q) * 1024 + (uint64_t)row * 16;

#define HMFMA(S) acc = __builtin_amdgcn_mfma_f32_32x32x16_bf16( \
    __builtin_bit_cast(bf16x8, abuf[S]), ubf[S], acc, 0, 0, 0)

  for (int t = 0; t < T_STEPS; ++t) {
    f32x16 acc = {0.f,0.f,0.f,0.f,0.f,0.f,0.f,0.f,0.f,0.f,0.f,0.f,0.f,0.f,0.f,0.f};

    // ---- x_t @ W (cached loads; overlaps other blocks finishing t-1) ----
    const u16* xa = xb + (size_t)t * (BATCH * DIN) + row * DIN + ks * 128 + q * 8;
#pragma unroll
    for (int s = 0; s < 8; ++s) {
      bf16x8 av = *(const bf16x8*)(xa + s * 16);
      acc = __builtin_amdgcn_mfma_f32_32x32x16_bf16(av, wbf[s], acc, 0, 0, 0);
    }

    // ---- poll (every wave; no broadcast barrier) ----
    while (true) {
      unsigned f1 = load4_sc(fbase + l * 16);
      unsigned f2 = load4_sc(fbase + 1024 + l * 16);
      WAITV(0);
      if (__all(f1 >= (unsigned)t && f2 >= (unsigned)t)) break;
      __builtin_amdgcn_s_sleep(1);
    }

    // ---- h_t @ U: 16 sc1 loads in flight, counted vmcnt ----
    const uint64_t hb = (uint64_t)hbuf + (uint64_t)(t & 1) * (BATCH * HID * 2) + hlane;
    uint32x4 abuf[16];
#pragma unroll
    for (int s = 0; s < 16; ++s) abuf[s] = load16_sc(hb + (uint64_t)s * 2048);
    WAITV(12); __builtin_amdgcn_sched_barrier(0);
    HMFMA(0); HMFMA(1); HMFMA(2); HMFMA(3);
    WAITV(8); __builtin_amdgcn_sched_barrier(0);
    HMFMA(4); HMFMA(5); HMFMA(6); HMFMA(7);
    WAITV(4); __builtin_amdgcn_sched_barrier(0);
    HMFMA(8); HMFMA(9); HMFMA(10); HMFMA(11);
    WAITV(0); __builtin_amdgcn_sched_barrier(0);
    HMFMA(12); HMFMA(13); HMFMA(14); HMFMA(15);

    // ---- K-split partial -> LDS (C layout: col=l&31, row=(r&3)+8*(r>>2)+4*q) ----
#pragma unroll
    for (int r = 0; r < 16; ++r) {
      int rl = (r & 3) + 8 * (r >> 2) + 4 * q;
      zp[ks * 2112 + (m_t * 32 + rl) * 33 + cl] = acc[r];
    }
    __syncthreads();

    // ---- reduce partials + gates: one thread per (batch, unit) ----
    float zi = bi, zf = bf_, zg = bg, zo = bo;
#pragma unroll
    for (int k2 = 0; k2 < 4; ++k2) {
      const float* zr = zp + k2 * 2112 + pb * 33;
      zi += zr[pu]; zf += zr[pu + 8]; zg += zr[pu + 16]; zo += zr[pu + 24];
    }
    float ig = sigm(zi), fg = sigm(zf), og = sigm(zo);
    float gg = fast_tanh(zg);
    c_reg = fg * c_reg + ig * gg;
    float h = og * fast_tanh(c_reg);
    hstage[pb * 8 + pu] = f2bf(h);
    if (t == T_STEPS - 1) {
      float* orow = out + (size_t)pb * 3072 + j0 + pu;
      orow[0]    = h;       // h_T
      orow[1024] = h;       // h_T again
      orow[2048] = c_reg;   // c_T
    }
    __syncthreads();              // hstage complete; zpart reads done

    // ---- publish h_{t+1}: wave 0; release via waitcnt (no cache maintenance) ----
    if (wv == 0) {
      uint32x4 hv = *reinterpret_cast<const uint32x4*>(&hstage[l * 8]);
      uint64_t hbn = (uint64_t)hbuf + (uint64_t)((t + 1) & 1) * (BATCH * HID * 2);
      store16_sc(hbn + (uint64_t)bid * 1024 + (uint64_t)l * 16, hv);
      WAITV(0);
      if (l == 0) store4_sc(fbase + (uint64_t)bid * 16, (unsigned)(t + 1));
    }
  }
#undef HMFMA
}

extern "C" void kernel_launch(void* const* d_in, const int* in_sizes, int n_in,
                              void* d_out, int out_size, void* d_ws, size_t ws_size,
                              hipStream_t stream) {
  const float* x = (const float*)d_in[0];
  const float* W = (const float*)d_in[1];
  const float* U = (const float*)d_in[2];
  const float* b = (const float*)d_in[3];
  float* out = (float*)d_out;

  const size_t xb_bytes   = (size_t)T_STEPS * BATCH * DIN * sizeof(u16);  // 32 MB
  const size_t hbuf_bytes = 2ull * BATCH * HID * sizeof(u16);             // 256 KB
  const size_t flag_bytes = NBLK * 16;                                    // 2 KB
  if (ws_size < xb_bytes + hbuf_bytes + flag_bytes) return;

  u16* xb         = (u16*)d_ws;
  u16* hbuf       = (u16*)((char*)d_ws + xb_bytes);
  unsigned* flags = (unsigned*)((char*)d_ws + xb_bytes + hbuf_bytes);

  // zero h0 (both buffers) + flags — replayed every graph launch
  hipMemsetAsync((void*)hbuf, 0, hbuf_bytes + flag_bytes, stream);
  cvt_x<<<(T_STEPS * BATCH * DIN / 8 + 255) / 256, 256, 0, stream>>>(x, xb);
  lstm_kernel<<<NBLK, THREADS, 0, stream>>>(W, U, b, xb, hbuf, out, flags);
}

// Round 6
// 2655.868 us; speedup vs baseline: 4.9561x; 1.0891x over previous
//
#include <hip/hip_runtime.h>
#include <stdint.h>

typedef unsigned short u16;

#define T_STEPS 512
#define BATCH   64
#define DIN     512
#define HID     1024
#define G4      4096   // 4*HID
#define NBLK    128
#define NH      8      // hidden units per block
#define NC      32     // gate columns per block (4*NH)
#define THREADS 512

#define U_LD    1032   // 1024 + 8 pad (init staging only)
#define W_LD    520    // 512 + 8 pad  (init staging only)

// LDS: init phase  Ut[NC*U_LD] @0 (66048B), Wt[NC*W_LD] @66048 (33280B)
//      run  phase  zpart f32[4][64][33] @0 (33792B), hstage u16[512] @33792 (1024B)
#define SM_BYTES 99328
#define WT_OFF   66048
#define HS_OFF   33792

typedef float f32x16 __attribute__((ext_vector_type(16)));
typedef short bf16x8 __attribute__((ext_vector_type(8)));
typedef unsigned uint32x4 __attribute__((ext_vector_type(4)));

__device__ __forceinline__ u16 f2bf(float f) {
  unsigned u = __float_as_uint(f);
  u += 0x7fffu + ((u >> 16) & 1u);   // RNE
  return (u16)(u >> 16);
}
__device__ __forceinline__ float sigm(float x) {
  return __builtin_amdgcn_rcpf(1.f + __expf(-x));
}
__device__ __forceinline__ float fast_tanh(float x) {
  return 1.f - 2.f * __builtin_amdgcn_rcpf(__expf(2.f * x) + 1.f);
}

// Coherent (L2-bypass, served at coherence point) helpers; flat 64b VGPR addr.
__device__ __forceinline__ uint32x4 load16_sc(uint64_t addr) {
  uint32x4 d;
  asm volatile("global_load_dwordx4 %0, %1, off sc0 sc1" : "=v"(d) : "v"(addr));
  return d;
}
__device__ __forceinline__ unsigned load4_sc(uint64_t addr) {
  unsigned d;
  asm volatile("global_load_dword %0, %1, off sc0 sc1" : "=v"(d) : "v"(addr));
  return d;
}
__device__ __forceinline__ void store16_sc(uint64_t addr, uint32x4 v) {
  asm volatile("global_store_dwordx4 %0, %1, off sc0 sc1" :: "v"(addr), "v"(v) : "memory");
}
__device__ __forceinline__ void store4_sc(uint64_t addr, unsigned v) {
  asm volatile("global_store_dword %0, %1, off sc0 sc1" :: "v"(addr), "v"(v) : "memory");
}
#define WAITV(n) asm volatile("s_waitcnt vmcnt(" #n ")" ::: "memory")

// x[B][T][D] fp32 -> xb[T][B][D] bf16
__global__ void cvt_x(const float* __restrict__ x, u16* __restrict__ xb) {
  int i = blockIdx.x * 256 + threadIdx.x;
  int dblk = i & 63;
  int rest = i >> 6;
  int b = rest & 63;
  int t = rest >> 6;
  const float4* s = reinterpret_cast<const float4*>(x + ((size_t)(b * T_STEPS + t)) * DIN + dblk * 8);
  float4 f0 = s[0], f1 = s[1];
  uint4 o;
  o.x = (unsigned)f2bf(f0.x) | ((unsigned)f2bf(f0.y) << 16);
  o.y = (unsigned)f2bf(f0.z) | ((unsigned)f2bf(f0.w) << 16);
  o.z = (unsigned)f2bf(f1.x) | ((unsigned)f2bf(f1.y) << 16);
  o.w = (unsigned)f2bf(f1.z) | ((unsigned)f2bf(f1.w) << 16);
  *reinterpret_cast<uint4*>(xb + ((size_t)(t * BATCH + b)) * DIN + dblk * 8) = o;
}

// Persistent LSTM. Block bid owns hidden units [bid*8, bid*8+8).
// GEMM: 32x32x16 MFMA, 8 waves = 2 M-tiles x 4 K-splits; B-frags in registers;
// K-split partials reduced through LDS (zpart). h layout [kblk=128][b=64][8] bf16.
// Fine-grained sync: wave ks polls ONLY the 32 producer flags it consumes.
__launch_bounds__(THREADS)
__global__ void lstm_kernel(const float* __restrict__ W, const float* __restrict__ U,
                            const float* __restrict__ bias, const u16* __restrict__ xb,
                            u16* __restrict__ hbuf, float* __restrict__ out,
                            unsigned* __restrict__ flags) {
  __shared__ __align__(16) char smraw[SM_BYTES];
  u16* Ut = (u16*)smraw;
  u16* Wt = (u16*)(smraw + WT_OFF);
  float* zp = (float*)smraw;              // run phase: [4][64][33]
  u16* hstage = (u16*)(smraw + HS_OFF);   // run phase: [64][8]

  const int tid = threadIdx.x;
  const int bid = blockIdx.x;
  const int j0 = bid * NH;

  // ---- init: stage transposed bf16 weight slices ----
  for (int idx = tid; idx < NC * HID; idx += THREADS) {
    int c = idx & (NC - 1);
    int k = idx >> 5;
    int gcol = ((c >> 3) << 10) + j0 + (c & 7);
    Ut[c * U_LD + k] = f2bf(U[(size_t)k * G4 + gcol]);
  }
  for (int idx = tid; idx < NC * DIN; idx += THREADS) {
    int c = idx & (NC - 1);
    int k = idx >> 5;
    int gcol = ((c >> 3) << 10) + j0 + (c & 7);
    Wt[c * W_LD + k] = f2bf(W[(size_t)k * G4 + gcol]);
  }
  __syncthreads();

  // ---- wave geometry: wv = (ks<<1)|m_t ----
  const int l   = tid & 63;
  const int wv  = tid >> 6;
  const int m_t = wv & 1;          // batch rows m_t*32 .. +31
  const int ks  = wv >> 1;         // K-split 0..3 (256 of HID, 128 of DIN each)
  const int cl  = l & 31;          // A row within tile / B column
  const int q   = l >> 5;          // k-half of fragment

  // ---- persistent B fragments -> registers ----
  bf16x8 ubf[16], wbf[8];
  {
    const u16* ub = Ut + cl * U_LD + ks * 256 + q * 8;
#pragma unroll
    for (int s = 0; s < 16; ++s) ubf[s] = *(const bf16x8*)(ub + s * 16);
    const u16* wb = Wt + cl * W_LD + ks * 128 + q * 8;
#pragma unroll
    for (int s = 0; s < 8; ++s) wbf[s] = *(const bf16x8*)(wb + s * 16);
  }
  __syncthreads();   // staging dead; zpart/hstage live from here

  const int row = m_t * 32 + cl;   // batch row this lane loads for A
  const int pb = tid & 63;         // gates: batch
  const int pu = tid >> 6;         // gates: unit
  float c_reg = 0.f;
  const float bi  = bias[j0 + pu];
  const float bf_ = bias[1024 + j0 + pu];
  const float bg  = bias[2048 + j0 + pu];
  const float bo  = bias[3072 + j0 + pu];

  const uint64_t fbase = (uint64_t)flags;
  // per-lane poll address: the ONE producer flag this lane's wave-k-slice needs
  const uint64_t faddr = fbase + (uint64_t)(ks * 32 + cl) * 16;
  // h A-frag: kblk = ks*32 + s*2 + q, byte = kblk*1024 + row*16
  const uint64_t hlane = (uint64_t)(ks * 32 + q) * 1024 + (uint64_t)row * 16;

#define HMFMA(S) acc = __builtin_amdgcn_mfma_f32_32x32x16_bf16( \
    __builtin_bit_cast(bf16x8, abuf[S]), ubf[S], acc, 0, 0, 0)

  for (int t = 0; t < T_STEPS; ++t) {
    f32x16 acc = {0.f,0.f,0.f,0.f,0.f,0.f,0.f,0.f,0.f,0.f,0.f,0.f,0.f,0.f,0.f,0.f};

    // ---- x_t @ W (cached loads; overlaps other blocks finishing t-1) ----
    const u16* xa = xb + (size_t)t * (BATCH * DIN) + row * DIN + ks * 128 + q * 8;
#pragma unroll
    for (int s = 0; s < 8; ++s) {
      bf16x8 av = *(const bf16x8*)(xa + s * 16);
      acc = __builtin_amdgcn_mfma_f32_32x32x16_bf16(av, wbf[s], acc, 0, 0, 0);
    }

    // ---- fine-grained poll: one flag per lane, this wave's 32 producers ----
    while (true) {
      unsigned f = load4_sc(faddr);
      WAITV(0);
      if (__all(f >= (unsigned)t)) break;
      __builtin_amdgcn_s_sleep(1);
    }

    // ---- h_t @ U: 16 sc1 loads in flight, counted vmcnt ----
    const uint64_t hb = (uint64_t)hbuf + (uint64_t)(t & 1) * (BATCH * HID * 2) + hlane;
    uint32x4 abuf[16];
#pragma unroll
    for (int s = 0; s < 16; ++s) abuf[s] = load16_sc(hb + (uint64_t)s * 2048);
    WAITV(12); __builtin_amdgcn_sched_barrier(0);
    HMFMA(0); HMFMA(1); HMFMA(2); HMFMA(3);
    WAITV(8); __builtin_amdgcn_sched_barrier(0);
    HMFMA(4); HMFMA(5); HMFMA(6); HMFMA(7);
    WAITV(4); __builtin_amdgcn_sched_barrier(0);
    HMFMA(8); HMFMA(9); HMFMA(10); HMFMA(11);
    WAITV(0); __builtin_amdgcn_sched_barrier(0);
    HMFMA(12); HMFMA(13); HMFMA(14); HMFMA(15);

    // ---- K-split partial -> LDS (C layout: col=l&31, row=(r&3)+8*(r>>2)+4*q) ----
#pragma unroll
    for (int r = 0; r < 16; ++r) {
      int rl = (r & 3) + 8 * (r >> 2) + 4 * q;
      zp[ks * 2112 + (m_t * 32 + rl) * 33 + cl] = acc[r];
    }
    __syncthreads();

    // ---- reduce partials + gates: one thread per (batch, unit) ----
    float zi = bi, zf = bf_, zg = bg, zo = bo;
#pragma unroll
    for (int k2 = 0; k2 < 4; ++k2) {
      const float* zr = zp + k2 * 2112 + pb * 33;
      zi += zr[pu]; zf += zr[pu + 8]; zg += zr[pu + 16]; zo += zr[pu + 24];
    }
    float ig = sigm(zi), fg = sigm(zf), og = sigm(zo);
    float gg = fast_tanh(zg);
    c_reg = fg * c_reg + ig * gg;
    float h = og * fast_tanh(c_reg);
    hstage[pb * 8 + pu] = f2bf(h);
    if (t == T_STEPS - 1) {
      float* orow = out + (size_t)pb * 3072 + j0 + pu;
      orow[0]    = h;       // h_T
      orow[1024] = h;       // h_T again
      orow[2048] = c_reg;   // c_T
    }
    __syncthreads();              // hstage complete; zpart reads done

    // ---- publish h_{t+1}: wave 0; release via waitcnt (no cache maintenance) ----
    if (wv == 0) {
      uint32x4 hv = *reinterpret_cast<const uint32x4*>(&hstage[l * 8]);
      uint64_t hbn = (uint64_t)hbuf + (uint64_t)((t + 1) & 1) * (BATCH * HID * 2);
      store16_sc(hbn + (uint64_t)bid * 1024 + (uint64_t)l * 16, hv);
      WAITV(0);
      if (l == 0) store4_sc(fbase + (uint64_t)bid * 16, (unsigned)(t + 1));
    }
  }
#undef HMFMA
}

extern "C" void kernel_launch(void* const* d_in, const int* in_sizes, int n_in,
                              void* d_out, int out_size, void* d_ws, size_t ws_size,
                              hipStream_t stream) {
  const float* x = (const float*)d_in[0];
  const float* W = (const float*)d_in[1];
  const float* U = (const float*)d_in[2];
  const float* b = (const float*)d_in[3];
  float* out = (float*)d_out;

  const size_t xb_bytes   = (size_t)T_STEPS * BATCH * DIN * sizeof(u16);  // 32 MB
  const size_t hbuf_bytes = 2ull * BATCH * HID * sizeof(u16);             // 256 KB
  const size_t flag_bytes = NBLK * 16;                                    // 2 KB
  if (ws_size < xb_bytes + hbuf_bytes + flag_bytes) return;

  u16* xb         = (u16*)d_ws;
  u16* hbuf       = (u16*)((char*)d_ws + xb_bytes);
  unsigned* flags = (unsigned*)((char*)d_ws + xb_bytes + hbuf_bytes);

  // zero h0 (both buffers) + flags — replayed every graph launch
  hipMemsetAsync((void*)hbuf, 0, hbuf_bytes + flag_bytes, stream);
  cvt_x<<<(T_STEPS * BATCH * DIN / 8 + 255) / 256, 256, 0, stream>>>(x, xb);
  lstm_kernel<<<NBLK, THREADS, 0, stream>>>(W, U, b, xb, hbuf, out, flags);
}